// Round 22
// baseline (147.112 us; speedup 1.0000x reference)
//
#include <hip/hip_runtime.h>
#include <hip/hip_bf16.h>
#include <stdint.h>

// Problem constants
#define B_SZ 2
#define T_SZ 2048
#define C_SZ 1024
#define H_SZ 16
#define HD   64
#define BH   (B_SZ * H_SZ)   // 32
#define M_SZ (B_SZ * T_SZ)   // 4096
#define N_QKV (3 * C_SZ)     // 3072

typedef __attribute__((ext_vector_type(8))) __bf16 bf16x8;
typedef __attribute__((ext_vector_type(4))) float f32x4;
typedef __attribute__((ext_vector_type(8))) unsigned short us8;
typedef __attribute__((ext_vector_type(4))) unsigned short us4;
typedef __attribute__((ext_vector_type(4))) unsigned int u32x4;

__device__ __forceinline__ unsigned short f2bf(float f) {
    unsigned int u = __builtin_bit_cast(unsigned int, f);
    u += 0x7fffu + ((u >> 16) & 1u);   // round-to-nearest-even
    return (unsigned short)(u >> 16);
}

// async global->LDS, 16B per lane; lds base must be wave-uniform (HW adds lane*16)
__device__ __forceinline__ void gll16(const unsigned short* g, unsigned short* l) {
    __builtin_amdgcn_global_load_lds(
        (const __attribute__((address_space(1))) unsigned int*)g,
        (__attribute__((address_space(3))) unsigned int*)l, 16, 0, 0);
}

// Barrier with EXPLICIT LDS-DMA drain (R7/R8 lesson: __syncthreads alone is not
// a reliable vmcnt(0) drain for in-flight global_load_lds in this structure).
__device__ __forceinline__ void hard_sync() {
    asm volatile("s_waitcnt vmcnt(0) lgkmcnt(0)" ::: "memory");
    __builtin_amdgcn_sched_barrier(0);
    __syncthreads();
}

// ---------------- prep: x->bf16 + both weight transposes (fused) ----------------
// grid: [0,2048) cvt x; [2048,5120) transpose w_attn; [5120,6144) transpose w_proj
__global__ __launch_bounds__(256) void k_prep(const float* __restrict__ x,
                                              const float* __restrict__ wa,
                                              const float* __restrict__ wp,
                                              unsigned short* __restrict__ xb,
                                              unsigned short* __restrict__ wta,
                                              unsigned short* __restrict__ wtp) {
    __shared__ float tile[32][33];
    const int tid = threadIdx.x;
    int idx = blockIdx.x;
    if (idx < 2048) {
        const size_t i = ((size_t)idx * 256 + tid) * 8;
        f32x4 a = *(const f32x4*)(x + i);
        f32x4 b = *(const f32x4*)(x + i + 4);
        us8 o;
        #pragma unroll
        for (int j = 0; j < 4; ++j) { o[j] = f2bf(a[j]); o[4 + j] = f2bf(b[j]); }
        *(us8*)(xb + i) = o;
        return;
    }
    const float* in; unsigned short* out; int N;
    if (idx < 5120) { idx -= 2048; in = wa; out = wta; N = N_QKV; }
    else            { idx -= 5120; in = wp; out = wtp; N = C_SZ; }
    const int nx = N / 32;
    const int n0 = (idx % nx) * 32, k0 = (idx / nx) * 32;
    const int tx = tid & 31, ty = tid >> 5;  // (32, 8)
    #pragma unroll
    for (int j = 0; j < 32; j += 8)
        tile[ty + j][tx] = in[(size_t)(k0 + ty + j) * N + (n0 + tx)];
    __syncthreads();
    #pragma unroll
    for (int j = 0; j < 32; j += 8)
        out[(size_t)(n0 + ty + j) * C_SZ + (k0 + tx)] = f2bf(tile[tx][ty + j]);
}

// ---------------- GEMM: C[M,N] = A[M,K](bf16) @ Bt[N,K]^T + bias ----------------
// Single-buffer BK=64, two hard_syncs per K-step (m97-class, R16-verified).
// TN=128: 4 waves as 2Mx2N (QKV). TN=64: 4 waves as 4Mx1N, 2 blocks/CU (proj).
template <int EPI, int TN>
__global__ __launch_bounds__(256) void k_gemm(const unsigned short* __restrict__ A,
                                              const unsigned short* __restrict__ Bt,
                                              const float* __restrict__ bias,
                                              float* __restrict__ Cout,
                                              unsigned short* __restrict__ q_ws,
                                              unsigned short* __restrict__ k_ws,
                                              unsigned short* __restrict__ vT_ws,
                                              int M, int N, int K, int NX) {
    constexpr int MI = (TN == 128) ? 4 : 2;       // M fragments per wave
    constexpr int BR = TN / 32;                   // B staging rounds
    __shared__ __attribute__((aligned(16))) unsigned short Ald[128 * 64];
    __shared__ __attribute__((aligned(16))) unsigned short Bld[TN * 64];
    const int tid = threadIdx.x;
    const int wid = tid >> 6, lane = tid & 63;
    const int wr = (TN == 128) ? (wid >> 1) : wid;
    const int wc = (TN == 128) ? (wid & 1) : 0;
    const int rbase = (TN == 128) ? wr * 64 : wr * 32;
    const int g = lane >> 4, l15 = lane & 15;
    const int nwg = gridDim.x;
    const int wg = (blockIdx.x & 7) * (nwg >> 3) + (blockIdx.x >> 3);
    const int m0 = (wg / NX) * 128, n0 = (wg % NX) * TN;

    f32x4 acc[MI][4];
    #pragma unroll
    for (int i = 0; i < MI; ++i)
        #pragma unroll
        for (int j = 0; j < 4; ++j) acc[i][j] = (f32x4){0.f, 0.f, 0.f, 0.f};

    for (int k0 = 0; k0 < K; k0 += 64) {
        hard_sync();
        #pragma unroll
        for (int i = 0; i < 4; ++i) {
            int c = i * 256 + tid;
            int row = c >> 3;
            int colb = ((c & 7) << 4) ^ ((row & 7) << 4);
            gll16(A + (size_t)(m0 + row) * K + k0 + (colb >> 1), Ald + i * 2048 + wid * 512);
        }
        #pragma unroll
        for (int i = 0; i < BR; ++i) {
            int c = i * 256 + tid;
            int row = c >> 3;
            int colb = ((c & 7) << 4) ^ ((row & 7) << 4);
            gll16(Bt + (size_t)(n0 + row) * K + k0 + (colb >> 1), Bld + i * 2048 + wid * 512);
        }
        hard_sync();

        #pragma unroll
        for (int ks = 0; ks < 2; ++ks) {
            bf16x8 af[MI], bfr[4];
            #pragma unroll
            for (int mi = 0; mi < MI; ++mi) {
                int row = rbase + mi * 16 + l15;
                af[mi] = *(const bf16x8*)((const char*)Ald + row * 128 +
                                          ((ks * 64 + g * 16) ^ ((row & 7) << 4)));
            }
            #pragma unroll
            for (int nj = 0; nj < 4; ++nj) {
                int row = wc * 64 + nj * 16 + l15;
                bfr[nj] = *(const bf16x8*)((const char*)Bld + row * 128 +
                                           ((ks * 64 + g * 16) ^ ((row & 7) << 4)));
            }
            #pragma unroll
            for (int mi = 0; mi < MI; ++mi)
                #pragma unroll
                for (int nj = 0; nj < 4; ++nj)
                    acc[mi][nj] = __builtin_amdgcn_mfma_f32_16x16x32_bf16(
                        af[mi], bfr[nj], acc[mi][nj], 0, 0, 0);
        }
    }

    if (EPI == 0) {
        #pragma unroll
        for (int nj = 0; nj < 4; ++nj) {
            int col = n0 + wc * 64 + nj * 16 + l15;
            float bv = bias[col];
            #pragma unroll
            for (int mi = 0; mi < MI; ++mi) {
                int rowb = m0 + rbase + mi * 16 + g * 4;
                #pragma unroll
                for (int r = 0; r < 4; ++r)
                    Cout[(size_t)(rowb + r) * N + col] = acc[mi][nj][r] + bv;
            }
        }
    } else {
        #pragma unroll
        for (int nj = 0; nj < 4; ++nj) {
            int col = n0 + wc * 64 + nj * 16 + l15;   // 0..3071
            float bv = bias[col];
            int which = col >> 10;
            int c10 = col & 1023;
            int h = c10 >> 6, d = c10 & 63;
            #pragma unroll
            for (int mi = 0; mi < MI; ++mi) {
                int row0 = m0 + rbase + mi * 16 + g * 4;     // multiple of 4
                int bb = row0 >> 11, t0 = row0 & 2047;
                if (which == 2) {
                    us4 pk;                                   // 4 consecutive t
                    #pragma unroll
                    for (int r = 0; r < 4; ++r) pk[r] = f2bf(acc[mi][nj][r] + bv);
                    *(us4*)&vT_ws[((size_t)(bb * H_SZ + h) * HD + d) * T_SZ + t0] = pk;
                } else {
                    #pragma unroll
                    for (int r = 0; r < 4; ++r)
                        (which ? k_ws : q_ws)[((size_t)(bb * H_SZ + h) * T_SZ + t0 + r) * HD + d] =
                            f2bf(acc[mi][nj][r] + bv);
                }
            }
        }
    }
}

// ---------------- causal flash attention, QBLK=256 (wave owns 32 q-rows) ----------
// R20 structure (verified correct) + __launch_bounds__(512, 2): only 1 block/CU
// ever runs (LDS 64KB), so cap occupancy at 2 waves/SIMD -> 256-VGPR budget,
// eliminating R20's spills. Each K/V fragment read feeds 2 MFMAs -> LDS read
// traffic per unit work halved. Pair {7-j, j} of 256-row tiles = 18 steps/block.
__global__ __launch_bounds__(512, 2) void k_attn(const unsigned short* __restrict__ q_ws,
                                                 const unsigned short* __restrict__ k_ws,
                                                 const unsigned short* __restrict__ vT_ws,
                                                 unsigned short* __restrict__ y_ws) {
    __shared__ __attribute__((aligned(16))) unsigned short Kbuf[2][8192];  // [128 keys][64 d]
    __shared__ __attribute__((aligned(16))) unsigned short Vbuf[2][8192];  // [64 d][128 t]
    const int tid = threadIdx.x;
    const int wid = tid >> 6, lane = tid & 63;
    const int g = lane >> 4, l15 = lane & 15;
    const int n = blockIdx.x;
    const int xcd = n & 7, j = (n >> 3) & 7, rk = n >> 6;
    const int bh = xcd + 8 * rk;
    const size_t kv_off = (size_t)bh * T_SZ * HD;
    const unsigned short* Kg = k_ws + kv_off;
    const unsigned short* Vg = vT_ws + (size_t)bh * HD * T_SZ;
    const int b = bh >> 4, h = bh & 15;
    const float SC = 0.125f * 1.44269504f;  // 1/sqrt(64) * log2(e)

    us8 ones_u;
    #pragma unroll
    for (int i = 0; i < 8; ++i) ones_u[i] = 0x3F80;
    const bf16x8 ones = __builtin_bit_cast(bf16x8, ones_u);

    auto stageK = [&](int kv, int buf) {        // 128x64 bf16, swz (row&7)<<4
        #pragma unroll
        for (int i = 0; i < 2; ++i) {
            int c = i * 512 + tid;
            int row = c >> 3;
            int colb = ((c & 7) << 4) ^ ((row & 7) << 4);
            gll16(Kg + (size_t)(kv * 128 + row) * HD + (colb >> 1),
                  &Kbuf[buf][i * 4096 + wid * 512]);
        }
    };
    auto stageV = [&](int kv, int buf) {        // 64x128 bf16 (V^T), swz (row&15)<<4
        #pragma unroll
        for (int i = 0; i < 2; ++i) {
            int c = i * 512 + tid;
            int row = c >> 4;                               // d index
            int colb = ((c & 15) << 4) ^ ((row & 15) << 4); // t-offset bytes in 256B row
            gll16(Vg + (size_t)row * T_SZ + kv * 128 + (colb >> 1),
                  &Vbuf[buf][i * 4096 + wid * 512]);
        }
    };

    #pragma unroll 1
    for (int phase = 0; phase < 2; ++phase) {
        const int qt = phase ? j : (7 - j);     // 256-row q-tile index
        const int nkv = 2 * (qt + 1);           // 128-key steps

        // Q fragments: wave owns rows qt*256 + wid*32 + qg*16 + l15, qg in {0,1}
        const int qrow0 = qt * 256 + wid * 32;
        bf16x8 aq[2][2];
        #pragma unroll
        for (int qg = 0; qg < 2; ++qg) {
            aq[qg][0] = *(const bf16x8*)(q_ws + kv_off + (size_t)(qrow0 + qg * 16 + l15) * HD + g * 8);
            aq[qg][1] = *(const bf16x8*)(q_ws + kv_off + (size_t)(qrow0 + qg * 16 + l15) * HD + 32 + g * 8);
        }

        float m_run[2] = {-3e38f, -3e38f};
        f32x4 acc[2][5];                        // per qg: [0..3] O, [4] l
        #pragma unroll
        for (int qg = 0; qg < 2; ++qg)
            #pragma unroll
            for (int dt = 0; dt < 5; ++dt) acc[qg][dt] = (f32x4){0.f, 0.f, 0.f, 0.f};

        stageK(0, 0); stageV(0, 0);
        hard_sync();

        for (int i = 0; i < nkv; ++i) {
            if (i + 1 < nkv) { stageK(i + 1, (i + 1) & 1); stageV(i + 1, (i + 1) & 1); }
            const char* Kb = (const char*)Kbuf[i & 1];
            const char* Vb = (const char*)Vbuf[i & 1];

            // QK^T: S^T rows = keys; one K-fragment read feeds both q-groups
            f32x4 st[8][2];
            __builtin_amdgcn_s_setprio(1);
            #pragma unroll
            for (int kt = 0; kt < 8; ++kt) {
                st[kt][0] = (f32x4){0.f, 0.f, 0.f, 0.f};
                st[kt][1] = (f32x4){0.f, 0.f, 0.f, 0.f};
                #pragma unroll
                for (int ks = 0; ks < 2; ++ks) {
                    int row = kt * 16 + l15;
                    bf16x8 ak = *(const bf16x8*)(Kb + row * 128 +
                                                 ((ks * 64 + g * 16) ^ ((row & 7) << 4)));
                    st[kt][0] = __builtin_amdgcn_mfma_f32_16x16x32_bf16(ak, aq[0][ks], st[kt][0], 0, 0, 0);
                    st[kt][1] = __builtin_amdgcn_mfma_f32_16x16x32_bf16(ak, aq[1][ks], st[kt][1], 0, 0, 0);
                }
            }
            __builtin_amdgcn_s_setprio(0);

            // softmax per q-group; diagonal spans the last two steps
            const bool diag = (i >= nkv - 2);
            const int moff = (i == nkv - 1) ? 128 : 0;
            u32x4 pf[2][4];
            #pragma unroll
            for (int qg = 0; qg < 2; ++qg) {
                const int qlq = wid * 32 + qg * 16 + l15;   // q row within 256-tile
                float t[32];
                #pragma unroll
                for (int kt = 0; kt < 8; ++kt)
                    #pragma unroll
                    for (int r = 0; r < 4; ++r) t[kt * 4 + r] = st[kt][qg][r];
                if (diag) {
                    #pragma unroll
                    for (int kt = 0; kt < 8; ++kt)
                        #pragma unroll
                        for (int r = 0; r < 4; ++r)
                            if (kt * 16 + g * 4 + r + moff > qlq) t[kt * 4 + r] = -3e38f;
                }
                float m16v[16];
                #pragma unroll
                for (int i2 = 0; i2 < 16; ++i2) m16v[i2] = fmaxf(t[i2], t[i2 + 16]);
                float m8v[8];
                #pragma unroll
                for (int i2 = 0; i2 < 8; ++i2) m8v[i2] = fmaxf(m16v[i2], m16v[i2 + 8]);
                float m4v[4];
                #pragma unroll
                for (int i2 = 0; i2 < 4; ++i2) m4v[i2] = fmaxf(m8v[i2], m8v[i2 + 4]);
                float mx = fmaxf(fmaxf(m4v[0], m4v[1]), fmaxf(m4v[2], m4v[3]));
                mx = fmaxf(mx, __shfl_xor(mx, 16, 64));
                mx = fmaxf(mx, __shfl_xor(mx, 32, 64));
                float mt = mx * SC;
                if (!__all(mt - m_run[qg] <= 8.0f)) {
                    float mnew = fmaxf(m_run[qg], mt);
                    float alpha = exp2f(m_run[qg] - mnew);   // uniform in 4-lane q-group
                    m_run[qg] = mnew;
                    float ao[4];
                    #pragma unroll
                    for (int r = 0; r < 4; ++r) {
                        int ai = __builtin_amdgcn_ds_bpermute((g * 4 + r) * 4,
                                                              __builtin_bit_cast(int, alpha));
                        ao[r] = __builtin_bit_cast(float, ai);
                    }
                    #pragma unroll
                    for (int dt = 0; dt < 5; ++dt)
                        #pragma unroll
                        for (int r = 0; r < 4; ++r) acc[qg][dt][r] *= ao[r];
                }
                float p[32];
                #pragma unroll
                for (int i2 = 0; i2 < 32; ++i2) p[i2] = exp2f(fmaf(t[i2], SC, -m_run[qg]));
                #pragma unroll
                for (int ks = 0; ks < 4; ++ks) {
                    unsigned int x0, y0, x1, y1;
                    asm("v_cvt_pk_bf16_f32 %0, %1, %2" : "=v"(x0) : "v"(p[8 * ks + 0]), "v"(p[8 * ks + 1]));
                    asm("v_cvt_pk_bf16_f32 %0, %1, %2" : "=v"(x1) : "v"(p[8 * ks + 2]), "v"(p[8 * ks + 3]));
                    asm("v_cvt_pk_bf16_f32 %0, %1, %2" : "=v"(y0) : "v"(p[8 * ks + 4]), "v"(p[8 * ks + 5]));
                    asm("v_cvt_pk_bf16_f32 %0, %1, %2" : "=v"(y1) : "v"(p[8 * ks + 6]), "v"(p[8 * ks + 7]));
                    asm("v_permlane32_swap_b32 %0, %1" : "+v"(x0), "+v"(y0));
                    asm("v_permlane16_swap_b32 %0, %1" : "+v"(x0), "+v"(y0));
                    asm("v_permlane32_swap_b32 %0, %1" : "+v"(x1), "+v"(y1));
                    asm("v_permlane16_swap_b32 %0, %1" : "+v"(x1), "+v"(y1));
                    pf[qg][ks] = (u32x4){x0, x1, y0, y1};
                }
            }

            // PV: one V-fragment read feeds both q-groups; ones-MFMA accumulates l
            __builtin_amdgcn_s_setprio(1);
            #pragma unroll
            for (int ks = 0; ks < 4; ++ks) {
                bf16x8 ap0 = __builtin_bit_cast(bf16x8, pf[0][ks]);
                bf16x8 ap1 = __builtin_bit_cast(bf16x8, pf[1][ks]);
                #pragma unroll
                for (int dt = 0; dt < 4; ++dt) {
                    int row = dt * 16 + l15;
                    bf16x8 bv = *(const bf16x8*)(Vb + row * 256 +
                                                 ((ks * 64 + g * 16) ^ ((row & 15) << 4)));
                    acc[0][dt] = __builtin_amdgcn_mfma_f32_16x16x32_bf16(ap0, bv, acc[0][dt], 0, 0, 0);
                    acc[1][dt] = __builtin_amdgcn_mfma_f32_16x16x32_bf16(ap1, bv, acc[1][dt], 0, 0, 0);
                }
                acc[0][4] = __builtin_amdgcn_mfma_f32_16x16x32_bf16(ap0, ones, acc[0][4], 0, 0, 0);
                acc[1][4] = __builtin_amdgcn_mfma_f32_16x16x32_bf16(ap1, ones, acc[1][4], 0, 0, 0);
            }
            __builtin_amdgcn_s_setprio(0);

            hard_sync();          // drains next-step DMA; frees this step's buffers
        }

        // epilogue: l per-lane in acc[qg][4] (row=4g+r); normalize, store
        #pragma unroll
        for (int qg = 0; qg < 2; ++qg) {
            #pragma unroll
            for (int r = 0; r < 4; ++r) {
                int tq = qt * 256 + wid * 32 + qg * 16 + g * 4 + r;
                float inv = 1.0f / acc[qg][4][r];
                #pragma unroll
                for (int dt = 0; dt < 4; ++dt)
                    y_ws[(size_t)(b * T_SZ + tq) * C_SZ + h * 64 + dt * 16 + l15] =
                        f2bf(acc[qg][dt][r] * inv);
            }
        }
    }
}

// ---------------- launcher ----------------
extern "C" void kernel_launch(void* const* d_in, const int* in_sizes, int n_in,
                              void* d_out, int out_size, void* d_ws, size_t ws_size,
                              hipStream_t stream) {
    const float* x      = (const float*)d_in[0];
    const float* w_attn = (const float*)d_in[1];
    const float* b_attn = (const float*)d_in[2];
    const float* w_proj = (const float*)d_in[3];
    const float* b_proj = (const float*)d_in[4];
    float* out = (float*)d_out;

    char* ws = (char*)d_ws;
    unsigned short* q_ws  = (unsigned short*)(ws + 0);         // 8 MB [BH][T][HD]
    unsigned short* k_ws  = (unsigned short*)(ws + 8388608);   // 8 MB [BH][T][HD]
    unsigned short* vT_ws = (unsigned short*)(ws + 16777216);  // 8 MB [BH][HD][T]
    unsigned short* wtp   = (unsigned short*)(ws + 25165824);  // 2 MB [C][C]
    unsigned short* xb    = (unsigned short*)(ws + 27262976);  // 8 MB x as bf16
    unsigned short* y_ws  = (unsigned short*)(ws + 27262976);  // aliases xb (xb dead by then)
    unsigned short* wta   = (unsigned short*)(ws + 35651584);  // 6 MB [3C][C]

    // 1) fused prep: x->bf16 + both weight transposes
    k_prep<<<dim3(6144), 256, 0, stream>>>(x, w_attn, w_proj, xb, wta, wtp);

    // 2) QKV GEMM -> Q/K row-major + V^T   (tile 128x128, grid 768, %8==0)
    k_gemm<1, 128><<<dim3((N_QKV / 128) * (M_SZ / 128)), 256, 0, stream>>>(
        xb, wta, b_attn, nullptr, q_ws, k_ws, vT_ws, M_SZ, N_QKV, C_SZ, N_QKV / 128);

    // 3) causal flash attention -> y bf16 [B][T][C]  (256 blocks x 512 thr)
    k_attn<<<dim3(256), 512, 0, stream>>>(q_ws, k_ws, vT_ws, y_ws);

    // 4) proj GEMM: y @ w_proj + b_proj -> f32 out  (tile 128x64, grid 512, 2/CU)
    k_gemm<0, 64><<<dim3((C_SZ / 64) * (M_SZ / 128)), 256, 0, stream>>>(
        y_ws, wtp, b_proj, out, nullptr, nullptr, nullptr, M_SZ, C_SZ, C_SZ, C_SZ / 64);
}

// Round 23
// 105.378 us; speedup vs baseline: 1.3960x; 1.3960x over previous
//
#include <hip/hip_runtime.h>
#include <hip/hip_bf16.h>
#include <stdint.h>

// Problem constants
#define B_SZ 2
#define T_SZ 2048
#define C_SZ 1024
#define H_SZ 16
#define HD   64
#define BH   (B_SZ * H_SZ)   // 32
#define M_SZ (B_SZ * T_SZ)   // 4096
#define N_QKV (3 * C_SZ)     // 3072

typedef __attribute__((ext_vector_type(8))) __bf16 bf16x8;
typedef __attribute__((ext_vector_type(4))) float f32x4;
typedef __attribute__((ext_vector_type(8))) unsigned short us8;
typedef __attribute__((ext_vector_type(4))) unsigned short us4;
typedef __attribute__((ext_vector_type(4))) unsigned int u32x4;

__device__ __forceinline__ unsigned short f2bf(float f) {
    unsigned int u = __builtin_bit_cast(unsigned int, f);
    u += 0x7fffu + ((u >> 16) & 1u);   // round-to-nearest-even
    return (unsigned short)(u >> 16);
}

// async global->LDS, 16B per lane; lds base must be wave-uniform (HW adds lane*16)
__device__ __forceinline__ void gll16(const unsigned short* g, unsigned short* l) {
    __builtin_amdgcn_global_load_lds(
        (const __attribute__((address_space(1))) unsigned int*)g,
        (__attribute__((address_space(3))) unsigned int*)l, 16, 0, 0);
}

// Barrier with EXPLICIT LDS-DMA drain (R7/R8 lesson: __syncthreads alone is not
// a reliable vmcnt(0) drain for in-flight global_load_lds in this structure).
__device__ __forceinline__ void hard_sync() {
    asm volatile("s_waitcnt vmcnt(0) lgkmcnt(0)" ::: "memory");
    __builtin_amdgcn_sched_barrier(0);
    __syncthreads();
}

// ---------------- prep: x->bf16 + both weight transposes (fused) ----------------
// grid: [0,2048) cvt x; [2048,5120) transpose w_attn; [5120,6144) transpose w_proj
__global__ __launch_bounds__(256) void k_prep(const float* __restrict__ x,
                                              const float* __restrict__ wa,
                                              const float* __restrict__ wp,
                                              unsigned short* __restrict__ xb,
                                              unsigned short* __restrict__ wta,
                                              unsigned short* __restrict__ wtp) {
    __shared__ float tile[32][33];
    const int tid = threadIdx.x;
    int idx = blockIdx.x;
    if (idx < 2048) {
        const size_t i = ((size_t)idx * 256 + tid) * 8;
        f32x4 a = *(const f32x4*)(x + i);
        f32x4 b = *(const f32x4*)(x + i + 4);
        us8 o;
        #pragma unroll
        for (int j = 0; j < 4; ++j) { o[j] = f2bf(a[j]); o[4 + j] = f2bf(b[j]); }
        *(us8*)(xb + i) = o;
        return;
    }
    const float* in; unsigned short* out; int N;
    if (idx < 5120) { idx -= 2048; in = wa; out = wta; N = N_QKV; }
    else            { idx -= 5120; in = wp; out = wtp; N = C_SZ; }
    const int nx = N / 32;
    const int n0 = (idx % nx) * 32, k0 = (idx / nx) * 32;
    const int tx = tid & 31, ty = tid >> 5;  // (32, 8)
    #pragma unroll
    for (int j = 0; j < 32; j += 8)
        tile[ty + j][tx] = in[(size_t)(k0 + ty + j) * N + (n0 + tx)];
    __syncthreads();
    #pragma unroll
    for (int j = 0; j < 32; j += 8)
        out[(size_t)(n0 + ty + j) * C_SZ + (k0 + tx)] = f2bf(tile[tx][ty + j]);
}

// ---------------- GEMM: C[M,N] = A[M,K](bf16) @ Bt[N,K]^T + bias ----------------
// Single-buffer BK=64, two hard_syncs per K-step (m97-class, R16-verified).
// TN: tile N width. TN=128: 4 waves as 2Mx2N, acc 4x4 (QKV). TN=64: 4 waves as
// 4Mx1N, acc 2x4, grid doubles -> 2 blocks/CU for inter-block drain overlap (proj).
template <int EPI, int TN>
__global__ __launch_bounds__(256) void k_gemm(const unsigned short* __restrict__ A,
                                              const unsigned short* __restrict__ Bt,
                                              const float* __restrict__ bias,
                                              float* __restrict__ Cout,
                                              unsigned short* __restrict__ q_ws,
                                              unsigned short* __restrict__ k_ws,
                                              unsigned short* __restrict__ vT_ws,
                                              int M, int N, int K, int NX) {
    constexpr int MI = (TN == 128) ? 4 : 2;       // M fragments per wave
    constexpr int BR = TN / 32;                   // B staging rounds
    __shared__ __attribute__((aligned(16))) unsigned short Ald[128 * 64];
    __shared__ __attribute__((aligned(16))) unsigned short Bld[TN * 64];
    const int tid = threadIdx.x;
    const int wid = tid >> 6, lane = tid & 63;
    const int wr = (TN == 128) ? (wid >> 1) : wid;
    const int wc = (TN == 128) ? (wid & 1) : 0;
    const int rbase = (TN == 128) ? wr * 64 : wr * 32;
    const int g = lane >> 4, l15 = lane & 15;
    const int nwg = gridDim.x;
    const int wg = (blockIdx.x & 7) * (nwg >> 3) + (blockIdx.x >> 3);
    const int m0 = (wg / NX) * 128, n0 = (wg % NX) * TN;

    f32x4 acc[MI][4];
    #pragma unroll
    for (int i = 0; i < MI; ++i)
        #pragma unroll
        for (int j = 0; j < 4; ++j) acc[i][j] = (f32x4){0.f, 0.f, 0.f, 0.f};

    for (int k0 = 0; k0 < K; k0 += 64) {
        hard_sync();
        #pragma unroll
        for (int i = 0; i < 4; ++i) {
            int c = i * 256 + tid;
            int row = c >> 3;
            int colb = ((c & 7) << 4) ^ ((row & 7) << 4);
            gll16(A + (size_t)(m0 + row) * K + k0 + (colb >> 1), Ald + i * 2048 + wid * 512);
        }
        #pragma unroll
        for (int i = 0; i < BR; ++i) {
            int c = i * 256 + tid;
            int row = c >> 3;
            int colb = ((c & 7) << 4) ^ ((row & 7) << 4);
            gll16(Bt + (size_t)(n0 + row) * K + k0 + (colb >> 1), Bld + i * 2048 + wid * 512);
        }
        hard_sync();

        #pragma unroll
        for (int ks = 0; ks < 2; ++ks) {
            bf16x8 af[MI], bfr[4];
            #pragma unroll
            for (int mi = 0; mi < MI; ++mi) {
                int row = rbase + mi * 16 + l15;
                af[mi] = *(const bf16x8*)((const char*)Ald + row * 128 +
                                          ((ks * 64 + g * 16) ^ ((row & 7) << 4)));
            }
            #pragma unroll
            for (int nj = 0; nj < 4; ++nj) {
                int row = wc * 64 + nj * 16 + l15;
                bfr[nj] = *(const bf16x8*)((const char*)Bld + row * 128 +
                                           ((ks * 64 + g * 16) ^ ((row & 7) << 4)));
            }
            #pragma unroll
            for (int mi = 0; mi < MI; ++mi)
                #pragma unroll
                for (int nj = 0; nj < 4; ++nj)
                    acc[mi][nj] = __builtin_amdgcn_mfma_f32_16x16x32_bf16(
                        af[mi], bfr[nj], acc[mi][nj], 0, 0, 0);
        }
    }

    if (EPI == 0) {
        #pragma unroll
        for (int nj = 0; nj < 4; ++nj) {
            int col = n0 + wc * 64 + nj * 16 + l15;
            float bv = bias[col];
            #pragma unroll
            for (int mi = 0; mi < MI; ++mi) {
                int rowb = m0 + rbase + mi * 16 + g * 4;
                #pragma unroll
                for (int r = 0; r < 4; ++r)
                    Cout[(size_t)(rowb + r) * N + col] = acc[mi][nj][r] + bv;
            }
        }
    } else {
        #pragma unroll
        for (int nj = 0; nj < 4; ++nj) {
            int col = n0 + wc * 64 + nj * 16 + l15;   // 0..3071
            float bv = bias[col];
            int which = col >> 10;
            int c10 = col & 1023;
            int h = c10 >> 6, d = c10 & 63;
            #pragma unroll
            for (int mi = 0; mi < MI; ++mi) {
                int row0 = m0 + rbase + mi * 16 + g * 4;     // multiple of 4
                int bb = row0 >> 11, t0 = row0 & 2047;
                if (which == 2) {
                    us4 pk;                                   // 4 consecutive t
                    #pragma unroll
                    for (int r = 0; r < 4; ++r) pk[r] = f2bf(acc[mi][nj][r] + bv);
                    *(us4*)&vT_ws[((size_t)(bb * H_SZ + h) * HD + d) * T_SZ + t0] = pk;
                } else {
                    #pragma unroll
                    for (int r = 0; r < 4; ++r)
                        (which ? k_ws : q_ws)[((size_t)(bb * H_SZ + h) * T_SZ + t0 + r) * HD + d] =
                            f2bf(acc[mi][nj][r] + bv);
                }
            }
        }
    }
}

// ---------------- causal flash attention, QBLK=128 / KVBLK=128 / att[2] ----------
// 256 blocks (1/CU): xcd=n&7, j=(n>>3)&7, rk=n>>6. bh = xcd + 8*rk.
// Per iteration i: QK^T(i) ; PV(i-1) ; softmax(i). V triple-buffered.
// Balance is INTRA-block: sequential pair {15-j, j} -> exactly 17 steps/block.
// l computed by the PV MFMA via an all-ones B fragment (acc[4]).
__global__ __launch_bounds__(512) void k_attn(const unsigned short* __restrict__ q_ws,
                                              const unsigned short* __restrict__ k_ws,
                                              const unsigned short* __restrict__ vT_ws,
                                              unsigned short* __restrict__ y_ws) {
    __shared__ __attribute__((aligned(16))) unsigned short Kbuf[2][8192];  // [128 keys][64 d]
    __shared__ __attribute__((aligned(16))) unsigned short Vbuf[3][8192];  // [64 d][128 t]
    const int tid = threadIdx.x;
    const int wid = tid >> 6, lane = tid & 63;
    const int g = lane >> 4, l15 = lane & 15;
    const int n = blockIdx.x;
    const int xcd = n & 7, j = (n >> 3) & 7, rk = n >> 6;
    const int bh = xcd + 8 * rk;
    const size_t kv_off = (size_t)bh * T_SZ * HD;
    const unsigned short* Kg = k_ws + kv_off;
    const unsigned short* Vg = vT_ws + (size_t)bh * HD * T_SZ;
    const int b = bh >> 4, h = bh & 15;
    const float SC = 0.125f * 1.44269504f;  // 1/sqrt(64) * log2(e)
    const int qloc = wid * 16 + l15;        // q row within the 128-row tile

    // all-ones bf16 B fragment (valid for any operand layout)
    us8 ones_u;
    #pragma unroll
    for (int i = 0; i < 8; ++i) ones_u[i] = 0x3F80;
    const bf16x8 ones = __builtin_bit_cast(bf16x8, ones_u);

    auto stageK = [&](int kv, int buf) {        // 128x64 bf16, swz (row&7)<<4
        #pragma unroll
        for (int i = 0; i < 2; ++i) {
            int c = i * 512 + tid;
            int row = c >> 3;
            int colb = ((c & 7) << 4) ^ ((row & 7) << 4);
            gll16(Kg + (size_t)(kv * 128 + row) * HD + (colb >> 1),
                  &Kbuf[buf][i * 4096 + wid * 512]);
        }
    };
    auto stageV = [&](int kv, int buf) {        // 64x128 bf16 (V^T), swz (row&15)<<4
        #pragma unroll
        for (int i = 0; i < 2; ++i) {
            int c = i * 512 + tid;
            int row = c >> 4;                               // d index
            int colb = ((c & 15) << 4) ^ ((row & 15) << 4); // t-offset bytes in 256B row
            gll16(Vg + (size_t)row * T_SZ + kv * 128 + (colb >> 1),
                  &Vbuf[buf][i * 4096 + wid * 512]);
        }
    };

    #pragma unroll 1
    for (int phase = 0; phase < 2; ++phase) {
        const int qt = phase ? j : (15 - j);    // 128-row q-tile index
        const int nkv = qt + 1;                 // KV steps (128 keys each)

        const int qrow = qt * 128 + wid * 16 + l15;
        bf16x8 aq[2];
        aq[0] = *(const bf16x8*)(q_ws + kv_off + (size_t)qrow * HD + g * 8);
        aq[1] = *(const bf16x8*)(q_ws + kv_off + (size_t)qrow * HD + 32 + g * 8);

        float m_run = -3e38f;
        f32x4 acc[5];                           // [0..3]: O tiles; [4]: l (ones-row)
        #pragma unroll
        for (int dt = 0; dt < 5; ++dt) acc[dt] = (f32x4){0.f, 0.f, 0.f, 0.f};
        u32x4 pfA[4], pfB[4];

        auto qk = [&](const char* Kb, f32x4 (&st)[8]) {
            __builtin_amdgcn_s_setprio(1);
            #pragma unroll
            for (int kt = 0; kt < 8; ++kt) {
                f32x4 sv = (f32x4){0.f, 0.f, 0.f, 0.f};
                #pragma unroll
                for (int ks = 0; ks < 2; ++ks) {
                    int row = kt * 16 + l15;
                    bf16x8 ak = *(const bf16x8*)(Kb + row * 128 +
                                                 ((ks * 64 + g * 16) ^ ((row & 7) << 4)));
                    sv = __builtin_amdgcn_mfma_f32_16x16x32_bf16(ak, aq[ks], sv, 0, 0, 0);
                }
                st[kt] = sv;
            }
            __builtin_amdgcn_s_setprio(0);
        };
        auto pv = [&](const char* Vb, const u32x4 (&pf)[4]) {
            __builtin_amdgcn_s_setprio(1);
            #pragma unroll
            for (int ks = 0; ks < 4; ++ks) {
                bf16x8 ap = __builtin_bit_cast(bf16x8, pf[ks]);
                #pragma unroll
                for (int dt = 0; dt < 4; ++dt) {
                    int row = dt * 16 + l15;
                    bf16x8 bv = *(const bf16x8*)(Vb + row * 256 +
                                                 ((ks * 64 + g * 16) ^ ((row & 15) << 4)));
                    acc[dt] = __builtin_amdgcn_mfma_f32_16x16x32_bf16(ap, bv, acc[dt], 0, 0, 0);
                }
                acc[4] = __builtin_amdgcn_mfma_f32_16x16x32_bf16(ap, ones, acc[4], 0, 0, 0);
            }
            __builtin_amdgcn_s_setprio(0);
        };
        auto softmax = [&](f32x4 (&st)[8], bool diag, u32x4 (&pf)[4]) {
            float t[32];
            #pragma unroll
            for (int kt = 0; kt < 8; ++kt)
                #pragma unroll
                for (int r = 0; r < 4; ++r) t[kt * 4 + r] = st[kt][r];
            if (diag) {
                #pragma unroll
                for (int kt = 0; kt < 8; ++kt)
                    #pragma unroll
                    for (int r = 0; r < 4; ++r)
                        if (kt * 16 + g * 4 + r > qloc) t[kt * 4 + r] = -3e38f;
            }
            float m16v[16];
            #pragma unroll
            for (int i2 = 0; i2 < 16; ++i2) m16v[i2] = fmaxf(t[i2], t[i2 + 16]);
            float m8v[8];
            #pragma unroll
            for (int i2 = 0; i2 < 8; ++i2) m8v[i2] = fmaxf(m16v[i2], m16v[i2 + 8]);
            float m4v[4];
            #pragma unroll
            for (int i2 = 0; i2 < 4; ++i2) m4v[i2] = fmaxf(m8v[i2], m8v[i2 + 4]);
            float mx = fmaxf(fmaxf(m4v[0], m4v[1]), fmaxf(m4v[2], m4v[3]));
            mx = fmaxf(mx, __shfl_xor(mx, 16, 64));
            mx = fmaxf(mx, __shfl_xor(mx, 32, 64));
            float mt = mx * SC;
            if (!__all(mt - m_run <= 8.0f)) {
                float mnew = fmaxf(m_run, mt);
                float alpha = exp2f(m_run - mnew);   // uniform within 4-lane q-group
                m_run = mnew;
                float ao[4];
                #pragma unroll
                for (int r = 0; r < 4; ++r) {
                    int ai = __builtin_amdgcn_ds_bpermute((g * 4 + r) * 4,
                                                          __builtin_bit_cast(int, alpha));
                    ao[r] = __builtin_bit_cast(float, ai);
                }
                #pragma unroll
                for (int dt = 0; dt < 5; ++dt)       // includes l tile
                    #pragma unroll
                    for (int r = 0; r < 4; ++r) acc[dt][r] *= ao[r];
            }
            float p[32];
            #pragma unroll
            for (int i2 = 0; i2 < 32; ++i2) p[i2] = exp2f(fmaf(t[i2], SC, -m_run));
            #pragma unroll
            for (int ks = 0; ks < 4; ++ks) {
                unsigned int x0, y0, x1, y1;
                asm("v_cvt_pk_bf16_f32 %0, %1, %2" : "=v"(x0) : "v"(p[8 * ks + 0]), "v"(p[8 * ks + 1]));
                asm("v_cvt_pk_bf16_f32 %0, %1, %2" : "=v"(x1) : "v"(p[8 * ks + 2]), "v"(p[8 * ks + 3]));
                asm("v_cvt_pk_bf16_f32 %0, %1, %2" : "=v"(y0) : "v"(p[8 * ks + 4]), "v"(p[8 * ks + 5]));
                asm("v_cvt_pk_bf16_f32 %0, %1, %2" : "=v"(y1) : "v"(p[8 * ks + 6]), "v"(p[8 * ks + 7]));
                asm("v_permlane32_swap_b32 %0, %1" : "+v"(x0), "+v"(y0));
                asm("v_permlane16_swap_b32 %0, %1" : "+v"(x0), "+v"(y0));
                asm("v_permlane32_swap_b32 %0, %1" : "+v"(x1), "+v"(y1));
                asm("v_permlane16_swap_b32 %0, %1" : "+v"(x1), "+v"(y1));
                pf[ks] = (u32x4){x0, x1, y0, y1};
            }
        };

        hard_sync();              // all waves done reading buffers (prev phase)
        stageK(0, 0); stageV(0, 0);

        // peel i = 0: produce pfA, nothing to consume
        hard_sync();
        if (1 < nkv) { stageK(1, 1); stageV(1, 1); }
        {
            f32x4 st[8];
            qk((const char*)Kbuf[0], st);
            softmax(st, nkv == 1, pfA);
        }
        bool lastA = true;
        for (int i = 1; i < nkv; ) {
            hard_sync();
            if (i + 1 < nkv) { stageK(i + 1, (i + 1) & 1); stageV(i + 1, (i + 1) % 3); }
            {
                f32x4 st[8];
                qk((const char*)Kbuf[i & 1], st);
                pv((const char*)Vbuf[(i - 1) % 3], pfA);
                softmax(st, i == nkv - 1, pfB);
            }
            ++i; lastA = false; if (i == nkv) break;
            hard_sync();
            if (i + 1 < nkv) { stageK(i + 1, (i + 1) & 1); stageV(i + 1, (i + 1) % 3); }
            {
                f32x4 st[8];
                qk((const char*)Kbuf[i & 1], st);
                pv((const char*)Vbuf[(i - 1) % 3], pfB);
                softmax(st, i == nkv - 1, pfA);
            }
            ++i; lastA = true; if (i == nkv) break;
        }
        // tail: PV of the last tile (its V buffer is untouched after its stage)
        if (lastA) pv((const char*)Vbuf[(nkv - 1) % 3], pfA);
        else       pv((const char*)Vbuf[(nkv - 1) % 3], pfB);

        // epilogue: l is already per-lane in acc[4] (row=4g+r); normalize, store
        #pragma unroll
        for (int r = 0; r < 4; ++r) {
            int tq = qt * 128 + wid * 16 + g * 4 + r;
            float inv = 1.0f / acc[4][r];
            #pragma unroll
            for (int dt = 0; dt < 4; ++dt)
                y_ws[(size_t)(b * T_SZ + tq) * C_SZ + h * 64 + dt * 16 + l15] =
                    f2bf(acc[dt][r] * inv);
        }
    }
}

// ---------------- launcher ----------------
extern "C" void kernel_launch(void* const* d_in, const int* in_sizes, int n_in,
                              void* d_out, int out_size, void* d_ws, size_t ws_size,
                              hipStream_t stream) {
    const float* x      = (const float*)d_in[0];
    const float* w_attn = (const float*)d_in[1];
    const float* b_attn = (const float*)d_in[2];
    const float* w_proj = (const float*)d_in[3];
    const float* b_proj = (const float*)d_in[4];
    float* out = (float*)d_out;

    char* ws = (char*)d_ws;
    unsigned short* q_ws  = (unsigned short*)(ws + 0);         // 8 MB [BH][T][HD]
    unsigned short* k_ws  = (unsigned short*)(ws + 8388608);   // 8 MB [BH][T][HD]
    unsigned short* vT_ws = (unsigned short*)(ws + 16777216);  // 8 MB [BH][HD][T]
    unsigned short* wtp   = (unsigned short*)(ws + 25165824);  // 2 MB [C][C]
    unsigned short* xb    = (unsigned short*)(ws + 27262976);  // 8 MB x as bf16
    unsigned short* y_ws  = (unsigned short*)(ws + 27262976);  // aliases xb (xb dead by then)
    unsigned short* wta   = (unsigned short*)(ws + 35651584);  // 6 MB [3C][C]

    // 1) fused prep: x->bf16 + both weight transposes
    k_prep<<<dim3(6144), 256, 0, stream>>>(x, w_attn, w_proj, xb, wta, wtp);

    // 2) QKV GEMM -> Q/K row-major + V^T   (tile 128x128, grid 768, %8==0)
    k_gemm<1, 128><<<dim3((N_QKV / 128) * (M_SZ / 128)), 256, 0, stream>>>(
        xb, wta, b_attn, nullptr, q_ws, k_ws, vT_ws, M_SZ, N_QKV, C_SZ, N_QKV / 128);

    // 3) causal flash attention -> y bf16 [B][T][C]  (256 blocks x 512 thr)
    k_attn<<<dim3(256), 512, 0, stream>>>(q_ws, k_ws, vT_ws, y_ws);

    // 4) proj GEMM: y @ w_proj + b_proj -> f32 out  (tile 128x64, grid 512, 2/CU)
    k_gemm<0, 64><<<dim3((C_SZ / 64) * (M_SZ / 128)), 256, 0, stream>>>(
        y_ws, wtp, b_proj, out, nullptr, nullptr, nullptr, M_SZ, C_SZ, C_SZ, C_SZ / 64);
}

// Round 24
// 105.174 us; speedup vs baseline: 1.3987x; 1.0019x over previous
//
#include <hip/hip_runtime.h>
#include <hip/hip_bf16.h>
#include <stdint.h>

// Problem constants
#define B_SZ 2
#define T_SZ 2048
#define C_SZ 1024
#define H_SZ 16
#define HD   64
#define BH   (B_SZ * H_SZ)   // 32
#define M_SZ (B_SZ * T_SZ)   // 4096
#define N_QKV (3 * C_SZ)     // 3072

typedef __attribute__((ext_vector_type(8))) __bf16 bf16x8;
typedef __attribute__((ext_vector_type(4))) float f32x4;
typedef __attribute__((ext_vector_type(8))) unsigned short us8;
typedef __attribute__((ext_vector_type(4))) unsigned short us4;
typedef __attribute__((ext_vector_type(4))) unsigned int u32x4;

__device__ __forceinline__ unsigned short f2bf(float f) {
    unsigned int u = __builtin_bit_cast(unsigned int, f);
    u += 0x7fffu + ((u >> 16) & 1u);   // round-to-nearest-even
    return (unsigned short)(u >> 16);
}

// async global->LDS, 16B per lane; lds base must be wave-uniform (HW adds lane*16)
__device__ __forceinline__ void gll16(const unsigned short* g, unsigned short* l) {
    __builtin_amdgcn_global_load_lds(
        (const __attribute__((address_space(1))) unsigned int*)g,
        (__attribute__((address_space(3))) unsigned int*)l, 16, 0, 0);
}

// Barrier with EXPLICIT LDS-DMA drain (R7/R8 lesson: __syncthreads alone is not
// a reliable vmcnt(0) drain for in-flight global_load_lds in this structure).
__device__ __forceinline__ void hard_sync() {
    asm volatile("s_waitcnt vmcnt(0) lgkmcnt(0)" ::: "memory");
    __builtin_amdgcn_sched_barrier(0);
    __syncthreads();
}

// ---------------- prep: x->bf16 + both weight transposes (fused) ----------------
// grid: [0,2048) cvt x; [2048,5120) transpose w_attn; [5120,6144) transpose w_proj
__global__ __launch_bounds__(256) void k_prep(const float* __restrict__ x,
                                              const float* __restrict__ wa,
                                              const float* __restrict__ wp,
                                              unsigned short* __restrict__ xb,
                                              unsigned short* __restrict__ wta,
                                              unsigned short* __restrict__ wtp) {
    __shared__ float tile[32][33];
    const int tid = threadIdx.x;
    int idx = blockIdx.x;
    if (idx < 2048) {
        const size_t i = ((size_t)idx * 256 + tid) * 8;
        f32x4 a = *(const f32x4*)(x + i);
        f32x4 b = *(const f32x4*)(x + i + 4);
        us8 o;
        #pragma unroll
        for (int j = 0; j < 4; ++j) { o[j] = f2bf(a[j]); o[4 + j] = f2bf(b[j]); }
        *(us8*)(xb + i) = o;
        return;
    }
    const float* in; unsigned short* out; int N;
    if (idx < 5120) { idx -= 2048; in = wa; out = wta; N = N_QKV; }
    else            { idx -= 5120; in = wp; out = wtp; N = C_SZ; }
    const int nx = N / 32;
    const int n0 = (idx % nx) * 32, k0 = (idx / nx) * 32;
    const int tx = tid & 31, ty = tid >> 5;  // (32, 8)
    #pragma unroll
    for (int j = 0; j < 32; j += 8)
        tile[ty + j][tx] = in[(size_t)(k0 + ty + j) * N + (n0 + tx)];
    __syncthreads();
    #pragma unroll
    for (int j = 0; j < 32; j += 8)
        out[(size_t)(n0 + ty + j) * C_SZ + (k0 + tx)] = f2bf(tile[tx][ty + j]);
}

// ---------------- GEMM: C[M,N] = A[M,K](bf16) @ Bt[N,K]^T + bias ----------------
// Single-buffer BK=64, two hard_syncs per K-step (m97-class, R16-verified).
// TN: tile N width. TN=128: 4 waves as 2Mx2N, acc 4x4 (QKV). TN=64: 4 waves as
// 4Mx1N, acc 2x4, grid doubles -> 2 blocks/CU for inter-block drain overlap (proj).
template <int EPI, int TN>
__global__ __launch_bounds__(256) void k_gemm(const unsigned short* __restrict__ A,
                                              const unsigned short* __restrict__ Bt,
                                              const float* __restrict__ bias,
                                              float* __restrict__ Cout,
                                              unsigned short* __restrict__ q_ws,
                                              unsigned short* __restrict__ k_ws,
                                              unsigned short* __restrict__ vT_ws,
                                              int M, int N, int K, int NX) {
    constexpr int MI = (TN == 128) ? 4 : 2;       // M fragments per wave
    constexpr int BR = TN / 32;                   // B staging rounds
    __shared__ __attribute__((aligned(16))) unsigned short Ald[128 * 64];
    __shared__ __attribute__((aligned(16))) unsigned short Bld[TN * 64];
    const int tid = threadIdx.x;
    const int wid = tid >> 6, lane = tid & 63;
    const int wr = (TN == 128) ? (wid >> 1) : wid;
    const int wc = (TN == 128) ? (wid & 1) : 0;
    const int rbase = (TN == 128) ? wr * 64 : wr * 32;
    const int g = lane >> 4, l15 = lane & 15;
    const int nwg = gridDim.x;
    const int wg = (blockIdx.x & 7) * (nwg >> 3) + (blockIdx.x >> 3);
    const int m0 = (wg / NX) * 128, n0 = (wg % NX) * TN;

    f32x4 acc[MI][4];
    #pragma unroll
    for (int i = 0; i < MI; ++i)
        #pragma unroll
        for (int j = 0; j < 4; ++j) acc[i][j] = (f32x4){0.f, 0.f, 0.f, 0.f};

    for (int k0 = 0; k0 < K; k0 += 64) {
        hard_sync();
        #pragma unroll
        for (int i = 0; i < 4; ++i) {
            int c = i * 256 + tid;
            int row = c >> 3;
            int colb = ((c & 7) << 4) ^ ((row & 7) << 4);
            gll16(A + (size_t)(m0 + row) * K + k0 + (colb >> 1), Ald + i * 2048 + wid * 512);
        }
        #pragma unroll
        for (int i = 0; i < BR; ++i) {
            int c = i * 256 + tid;
            int row = c >> 3;
            int colb = ((c & 7) << 4) ^ ((row & 7) << 4);
            gll16(Bt + (size_t)(n0 + row) * K + k0 + (colb >> 1), Bld + i * 2048 + wid * 512);
        }
        hard_sync();

        #pragma unroll
        for (int ks = 0; ks < 2; ++ks) {
            bf16x8 af[MI], bfr[4];
            #pragma unroll
            for (int mi = 0; mi < MI; ++mi) {
                int row = rbase + mi * 16 + l15;
                af[mi] = *(const bf16x8*)((const char*)Ald + row * 128 +
                                          ((ks * 64 + g * 16) ^ ((row & 7) << 4)));
            }
            #pragma unroll
            for (int nj = 0; nj < 4; ++nj) {
                int row = wc * 64 + nj * 16 + l15;
                bfr[nj] = *(const bf16x8*)((const char*)Bld + row * 128 +
                                           ((ks * 64 + g * 16) ^ ((row & 7) << 4)));
            }
            #pragma unroll
            for (int mi = 0; mi < MI; ++mi)
                #pragma unroll
                for (int nj = 0; nj < 4; ++nj)
                    acc[mi][nj] = __builtin_amdgcn_mfma_f32_16x16x32_bf16(
                        af[mi], bfr[nj], acc[mi][nj], 0, 0, 0);
        }
    }

    if (EPI == 0) {
        #pragma unroll
        for (int nj = 0; nj < 4; ++nj) {
            int col = n0 + wc * 64 + nj * 16 + l15;
            float bv = bias[col];
            #pragma unroll
            for (int mi = 0; mi < MI; ++mi) {
                int rowb = m0 + rbase + mi * 16 + g * 4;
                #pragma unroll
                for (int r = 0; r < 4; ++r)
                    Cout[(size_t)(rowb + r) * N + col] = acc[mi][nj][r] + bv;
            }
        }
    } else {
        #pragma unroll
        for (int nj = 0; nj < 4; ++nj) {
            int col = n0 + wc * 64 + nj * 16 + l15;   // 0..3071
            float bv = bias[col];
            int which = col >> 10;
            int c10 = col & 1023;
            int h = c10 >> 6, d = c10 & 63;
            #pragma unroll
            for (int mi = 0; mi < MI; ++mi) {
                int row0 = m0 + rbase + mi * 16 + g * 4;     // multiple of 4
                int bb = row0 >> 11, t0 = row0 & 2047;
                if (which == 2) {
                    us4 pk;                                   // 4 consecutive t
                    #pragma unroll
                    for (int r = 0; r < 4; ++r) pk[r] = f2bf(acc[mi][nj][r] + bv);
                    *(us4*)&vT_ws[((size_t)(bb * H_SZ + h) * HD + d) * T_SZ + t0] = pk;
                } else {
                    #pragma unroll
                    for (int r = 0; r < 4; ++r)
                        (which ? k_ws : q_ws)[((size_t)(bb * H_SZ + h) * T_SZ + t0 + r) * HD + d] =
                            f2bf(acc[mi][nj][r] + bv);
                }
            }
        }
    }
}

// ---------------- causal flash attention, QBLK=128 / KVBLK=128 / att[2] ----------
// 256 blocks (1/CU): xcd=n&7, j=(n>>3)&7, rk=n>>6. bh = xcd + 8*rk.
// Per iteration i: QK^T(i) ; PV(i-1) ; softmax(i). V triple-buffered.
// Balance is INTRA-block: sequential pair {15-j, j} -> exactly 17 steps/block.
// l computed by the PV MFMA via an all-ones B fragment (acc[4]).
__global__ __launch_bounds__(512) void k_attn(const unsigned short* __restrict__ q_ws,
                                              const unsigned short* __restrict__ k_ws,
                                              const unsigned short* __restrict__ vT_ws,
                                              unsigned short* __restrict__ y_ws) {
    __shared__ __attribute__((aligned(16))) unsigned short Kbuf[2][8192];  // [128 keys][64 d]
    __shared__ __attribute__((aligned(16))) unsigned short Vbuf[3][8192];  // [64 d][128 t]
    const int tid = threadIdx.x;
    const int wid = tid >> 6, lane = tid & 63;
    const int g = lane >> 4, l15 = lane & 15;
    const int n = blockIdx.x;
    const int xcd = n & 7, j = (n >> 3) & 7, rk = n >> 6;
    const int bh = xcd + 8 * rk;
    const size_t kv_off = (size_t)bh * T_SZ * HD;
    const unsigned short* Kg = k_ws + kv_off;
    const unsigned short* Vg = vT_ws + (size_t)bh * HD * T_SZ;
    const int b = bh >> 4, h = bh & 15;
    const float SC = 0.125f * 1.44269504f;  // 1/sqrt(64) * log2(e)
    const int qloc = wid * 16 + l15;        // q row within the 128-row tile

    // all-ones bf16 B fragment (valid for any operand layout)
    us8 ones_u;
    #pragma unroll
    for (int i = 0; i < 8; ++i) ones_u[i] = 0x3F80;
    const bf16x8 ones = __builtin_bit_cast(bf16x8, ones_u);

    auto stageK = [&](int kv, int buf) {        // 128x64 bf16, swz (row&7)<<4
        #pragma unroll
        for (int i = 0; i < 2; ++i) {
            int c = i * 512 + tid;
            int row = c >> 3;
            int colb = ((c & 7) << 4) ^ ((row & 7) << 4);
            gll16(Kg + (size_t)(kv * 128 + row) * HD + (colb >> 1),
                  &Kbuf[buf][i * 4096 + wid * 512]);
        }
    };
    auto stageV = [&](int kv, int buf) {        // 64x128 bf16 (V^T), swz (row&15)<<4
        #pragma unroll
        for (int i = 0; i < 2; ++i) {
            int c = i * 512 + tid;
            int row = c >> 4;                               // d index
            int colb = ((c & 15) << 4) ^ ((row & 15) << 4); // t-offset bytes in 256B row
            gll16(Vg + (size_t)row * T_SZ + kv * 128 + (colb >> 1),
                  &Vbuf[buf][i * 4096 + wid * 512]);
        }
    };

    #pragma unroll 1
    for (int phase = 0; phase < 2; ++phase) {
        const int qt = phase ? j : (15 - j);    // 128-row q-tile index
        const int nkv = qt + 1;                 // KV steps (128 keys each)

        const int qrow = qt * 128 + wid * 16 + l15;
        bf16x8 aq[2];
        aq[0] = *(const bf16x8*)(q_ws + kv_off + (size_t)qrow * HD + g * 8);
        aq[1] = *(const bf16x8*)(q_ws + kv_off + (size_t)qrow * HD + 32 + g * 8);

        float m_run = -3e38f;
        f32x4 acc[5];                           // [0..3]: O tiles; [4]: l (ones-row)
        #pragma unroll
        for (int dt = 0; dt < 5; ++dt) acc[dt] = (f32x4){0.f, 0.f, 0.f, 0.f};
        u32x4 pfA[4], pfB[4];

        auto qk = [&](const char* Kb, f32x4 (&st)[8]) {
            __builtin_amdgcn_s_setprio(1);
            #pragma unroll
            for (int kt = 0; kt < 8; ++kt) {
                f32x4 sv = (f32x4){0.f, 0.f, 0.f, 0.f};
                #pragma unroll
                for (int ks = 0; ks < 2; ++ks) {
                    int row = kt * 16 + l15;
                    bf16x8 ak = *(const bf16x8*)(Kb + row * 128 +
                                                 ((ks * 64 + g * 16) ^ ((row & 7) << 4)));
                    sv = __builtin_amdgcn_mfma_f32_16x16x32_bf16(ak, aq[ks], sv, 0, 0, 0);
                }
                st[kt] = sv;
            }
            __builtin_amdgcn_s_setprio(0);
        };
        auto pv = [&](const char* Vb, const u32x4 (&pf)[4]) {
            __builtin_amdgcn_s_setprio(1);
            #pragma unroll
            for (int ks = 0; ks < 4; ++ks) {
                bf16x8 ap = __builtin_bit_cast(bf16x8, pf[ks]);
                #pragma unroll
                for (int dt = 0; dt < 4; ++dt) {
                    int row = dt * 16 + l15;
                    bf16x8 bv = *(const bf16x8*)(Vb + row * 256 +
                                                 ((ks * 64 + g * 16) ^ ((row & 15) << 4)));
                    acc[dt] = __builtin_amdgcn_mfma_f32_16x16x32_bf16(ap, bv, acc[dt], 0, 0, 0);
                }
                acc[4] = __builtin_amdgcn_mfma_f32_16x16x32_bf16(ap, ones, acc[4], 0, 0, 0);
            }
            __builtin_amdgcn_s_setprio(0);
        };
        auto softmax = [&](f32x4 (&st)[8], bool diag, u32x4 (&pf)[4]) {
            float t[32];
            #pragma unroll
            for (int kt = 0; kt < 8; ++kt)
                #pragma unroll
                for (int r = 0; r < 4; ++r) t[kt * 4 + r] = st[kt][r];
            if (diag) {
                #pragma unroll
                for (int kt = 0; kt < 8; ++kt)
                    #pragma unroll
                    for (int r = 0; r < 4; ++r)
                        if (kt * 16 + g * 4 + r > qloc) t[kt * 4 + r] = -3e38f;
            }
            float m16v[16];
            #pragma unroll
            for (int i2 = 0; i2 < 16; ++i2) m16v[i2] = fmaxf(t[i2], t[i2 + 16]);
            float m8v[8];
            #pragma unroll
            for (int i2 = 0; i2 < 8; ++i2) m8v[i2] = fmaxf(m16v[i2], m16v[i2 + 8]);
            float m4v[4];
            #pragma unroll
            for (int i2 = 0; i2 < 4; ++i2) m4v[i2] = fmaxf(m8v[i2], m8v[i2 + 4]);
            float mx = fmaxf(fmaxf(m4v[0], m4v[1]), fmaxf(m4v[2], m4v[3]));
            mx = fmaxf(mx, __shfl_xor(mx, 16, 64));
            mx = fmaxf(mx, __shfl_xor(mx, 32, 64));
            float mt = mx * SC;
            if (!__all(mt - m_run <= 8.0f)) {
                float mnew = fmaxf(m_run, mt);
                float alpha = exp2f(m_run - mnew);   // uniform within 4-lane q-group
                m_run = mnew;
                float ao[4];
                #pragma unroll
                for (int r = 0; r < 4; ++r) {
                    int ai = __builtin_amdgcn_ds_bpermute((g * 4 + r) * 4,
                                                          __builtin_bit_cast(int, alpha));
                    ao[r] = __builtin_bit_cast(float, ai);
                }
                #pragma unroll
                for (int dt = 0; dt < 5; ++dt)       // includes l tile
                    #pragma unroll
                    for (int r = 0; r < 4; ++r) acc[dt][r] *= ao[r];
            }
            float p[32];
            #pragma unroll
            for (int i2 = 0; i2 < 32; ++i2) p[i2] = exp2f(fmaf(t[i2], SC, -m_run));
            #pragma unroll
            for (int ks = 0; ks < 4; ++ks) {
                unsigned int x0, y0, x1, y1;
                asm("v_cvt_pk_bf16_f32 %0, %1, %2" : "=v"(x0) : "v"(p[8 * ks + 0]), "v"(p[8 * ks + 1]));
                asm("v_cvt_pk_bf16_f32 %0, %1, %2" : "=v"(x1) : "v"(p[8 * ks + 2]), "v"(p[8 * ks + 3]));
                asm("v_cvt_pk_bf16_f32 %0, %1, %2" : "=v"(y0) : "v"(p[8 * ks + 4]), "v"(p[8 * ks + 5]));
                asm("v_cvt_pk_bf16_f32 %0, %1, %2" : "=v"(y1) : "v"(p[8 * ks + 6]), "v"(p[8 * ks + 7]));
                asm("v_permlane32_swap_b32 %0, %1" : "+v"(x0), "+v"(y0));
                asm("v_permlane16_swap_b32 %0, %1" : "+v"(x0), "+v"(y0));
                asm("v_permlane32_swap_b32 %0, %1" : "+v"(x1), "+v"(y1));
                asm("v_permlane16_swap_b32 %0, %1" : "+v"(x1), "+v"(y1));
                pf[ks] = (u32x4){x0, x1, y0, y1};
            }
        };

        hard_sync();              // all waves done reading buffers (prev phase)
        stageK(0, 0); stageV(0, 0);

        // peel i = 0: produce pfA, nothing to consume
        hard_sync();
        if (1 < nkv) { stageK(1, 1); stageV(1, 1); }
        {
            f32x4 st[8];
            qk((const char*)Kbuf[0], st);
            softmax(st, nkv == 1, pfA);
        }
        bool lastA = true;
        for (int i = 1; i < nkv; ) {
            hard_sync();
            if (i + 1 < nkv) { stageK(i + 1, (i + 1) & 1); stageV(i + 1, (i + 1) % 3); }
            {
                f32x4 st[8];
                qk((const char*)Kbuf[i & 1], st);
                pv((const char*)Vbuf[(i - 1) % 3], pfA);
                softmax(st, i == nkv - 1, pfB);
            }
            ++i; lastA = false; if (i == nkv) break;
            hard_sync();
            if (i + 1 < nkv) { stageK(i + 1, (i + 1) & 1); stageV(i + 1, (i + 1) % 3); }
            {
                f32x4 st[8];
                qk((const char*)Kbuf[i & 1], st);
                pv((const char*)Vbuf[(i - 1) % 3], pfB);
                softmax(st, i == nkv - 1, pfA);
            }
            ++i; lastA = true; if (i == nkv) break;
        }
        // tail: PV of the last tile (its V buffer is untouched after its stage)
        if (lastA) pv((const char*)Vbuf[(nkv - 1) % 3], pfA);
        else       pv((const char*)Vbuf[(nkv - 1) % 3], pfB);

        // epilogue: l is already per-lane in acc[4] (row=4g+r); normalize, store
        #pragma unroll
        for (int r = 0; r < 4; ++r) {
            int tq = qt * 128 + wid * 16 + g * 4 + r;
            float inv = 1.0f / acc[4][r];
            #pragma unroll
            for (int dt = 0; dt < 4; ++dt)
                y_ws[(size_t)(b * T_SZ + tq) * C_SZ + h * 64 + dt * 16 + l15] =
                    f2bf(acc[dt][r] * inv);
        }
    }
}

// ---------------- launcher ----------------
extern "C" void kernel_launch(void* const* d_in, const int* in_sizes, int n_in,
                              void* d_out, int out_size, void* d_ws, size_t ws_size,
                              hipStream_t stream) {
    const float* x      = (const float*)d_in[0];
    const float* w_attn = (const float*)d_in[1];
    const float* b_attn = (const float*)d_in[2];
    const float* w_proj = (const float*)d_in[3];
    const float* b_proj = (const float*)d_in[4];
    float* out = (float*)d_out;

    char* ws = (char*)d_ws;
    unsigned short* q_ws  = (unsigned short*)(ws + 0);         // 8 MB [BH][T][HD]
    unsigned short* k_ws  = (unsigned short*)(ws + 8388608);   // 8 MB [BH][T][HD]
    unsigned short* vT_ws = (unsigned short*)(ws + 16777216);  // 8 MB [BH][HD][T]
    unsigned short* wtp   = (unsigned short*)(ws + 25165824);  // 2 MB [C][C]
    unsigned short* xb    = (unsigned short*)(ws + 27262976);  // 8 MB x as bf16
    unsigned short* y_ws  = (unsigned short*)(ws + 27262976);  // aliases xb (xb dead by then)
    unsigned short* wta   = (unsigned short*)(ws + 35651584);  // 6 MB [3C][C]

    // 1) fused prep: x->bf16 + both weight transposes
    k_prep<<<dim3(6144), 256, 0, stream>>>(x, w_attn, w_proj, xb, wta, wtp);

    // 2) QKV GEMM -> Q/K row-major + V^T   (tile 128x128, grid 768, %8==0)
    k_gemm<1, 128><<<dim3((N_QKV / 128) * (M_SZ / 128)), 256, 0, stream>>>(
        xb, wta, b_attn, nullptr, q_ws, k_ws, vT_ws, M_SZ, N_QKV, C_SZ, N_QKV / 128);

    // 3) causal flash attention -> y bf16 [B][T][C]  (256 blocks x 512 thr)
    k_attn<<<dim3(256), 512, 0, stream>>>(q_ws, k_ws, vT_ws, y_ws);

    // 4) proj GEMM: y @ w_proj + b_proj -> f32 out  (tile 128x64, grid 512, 2/CU)
    k_gemm<0, 64><<<dim3((C_SZ / 64) * (M_SZ / 128)), 256, 0, stream>>>(
        y_ws, wtp, b_proj, out, nullptr, nullptr, nullptr, M_SZ, C_SZ, C_SZ, C_SZ / 64);
}